// Round 4
// baseline (452.273 us; speedup 1.0000x reference)
//
#include <hip/hip_runtime.h>
#include <hip/hip_bf16.h>
#include <stdint.h>

#define B_    64
#define S_    2048
#define ENC_  512
#define ATTN_ 256

typedef __bf16 bf16;
typedef bf16  bf16x8 __attribute__((ext_vector_type(8)));
typedef bf16  bf16x4 __attribute__((ext_vector_type(4)));
typedef float f32x4  __attribute__((ext_vector_type(4)));

__device__ __forceinline__ float fexp2(float x) {
#if __has_builtin(__builtin_amdgcn_exp2f)
    return __builtin_amdgcn_exp2f(x);
#else
    return exp2f(x);
#endif
}
__device__ __forceinline__ float frcp(float x) {
#if __has_builtin(__builtin_amdgcn_rcpf)
    return __builtin_amdgcn_rcpf(x);
#else
    return 1.0f / x;
#endif
}
// tanh(x) = 1 - 2/(e^{2x}+1); overflow-safe (exp2->inf => 1, ->0 => -1)
__device__ __forceinline__ float fast_tanh(float x) {
    float e = fexp2(x * 2.8853900817779268f);
    return 1.0f - 2.0f * frcp(e + 1.0f);
}

__device__ __forceinline__ void async_copy16(const void* g, void* l) {
#if __has_builtin(__builtin_amdgcn_global_load_lds)
    __builtin_amdgcn_global_load_lds(
        (__attribute__((address_space(1))) void*)(g),
        (__attribute__((address_space(3))) void*)(l), 16, 0, 0);
#else
    *(uint4*)l = *(const uint4*)g;
#endif
}

// ---------------- setup: WT transpose->bf16 (blocks 0..511) + dec_proj (512..575)
__global__ __launch_bounds__(256) void k_setup(const float* __restrict__ W_enc,
                                               const float* __restrict__ dec_state,
                                               const float* __restrict__ W_dec,
                                               bf16* __restrict__ WT,
                                               float* __restrict__ dp) {
    int blk = blockIdx.x;
    if (blk < 512) {
        int idx = blk * 256 + threadIdx.x;      // 0..131071
        int n = idx >> 9;                        // /512
        int k = idx & 511;
        WT[idx] = (bf16)W_enc[k * ATTN_ + n];    // coalesced writes
    } else {
        int b = blk - 512;
        int a = threadIdx.x;
        const float* ds = dec_state + b * 512;
        float acc = 0.f;
#pragma unroll 8
        for (int d = 0; d < 512; ++d)
            acc += ds[d] * W_dec[d * ATTN_ + a];
        dp[b * ATTN_ + a] = acc;
    }
}

// ---------------- scores: GEMM(M=131072,K=512,N=256) + tanh.v epilogue ----
// Single-barrier pipelined K-loop: LDS double-buffered A+B; B(ks+1) via
// global_load_lds issued before the MFMAs; A register-prefetched 2 steps
// ahead with lane-contiguous loads (8 threads/row -> 8 lines per instr).
// Block tile M=128 x N=256, K-step 32, 4 waves as 2(m) x 2(n).
__global__ __launch_bounds__(256, 2) void k_scores(
    const float* __restrict__ enc,    // [131072][512]
    const bf16*  __restrict__ WT,     // [256][512] (n-major)
    const float* __restrict__ dp,     // [64][256]
    const float* __restrict__ v,      // [256]
    float* __restrict__ out_scores)   // [131072]
{
    __shared__ __align__(16) bf16 As[2][128 * 40];   // 2 x 10 KB, padded rows
    __shared__ __align__(16) bf16 Bs[2][256 * 32];   // 2 x 16 KB, chunk-swizzled
    __shared__ float partial[4][64];

    const int tid  = threadIdx.x;
    const int wave = tid >> 6;
    const int lane = tid & 63;
    const int l15  = lane & 15;
    const int q    = lane >> 4;
    const int m0   = blockIdx.x * 128;
    const int b    = blockIdx.x >> 4;            // 16 blocks per batch

    const int mrow0 = (wave >> 1) * 64;
    const int ncol0 = (wave & 1) * 128;

    float dpv[8], vv[8];
#pragma unroll
    for (int nt = 0; nt < 8; ++nt) {
        int col = ncol0 + nt * 16 + l15;
        dpv[nt] = dp[b * 256 + col];
        vv[nt]  = v[col];
    }

    const f32x4 zero4 = {0.f, 0.f, 0.f, 0.f};
    f32x4 acc[4][8];
#pragma unroll
    for (int mt = 0; mt < 4; ++mt)
#pragma unroll
        for (int nt = 0; nt < 8; ++nt)
            acc[mt][nt] = zero4;

    // A staging: 8 threads per row-chunk; thread covers 4 consecutive floats
    // in each of 4 row-groups (rows rg*32 + tid>>3).
    const int arow8 = tid >> 3;                  // 0..31
    const int acol8 = tid & 7;                   // 0..7
    const float* ag = enc + (size_t)(m0 + arow8) * 512 + acol8 * 4;

    // B staging: round r -> col c = r*64 + (tid>>2), chunk slot tid&3,
    // source chunk g = slot ^ ((c + (c>>2)) & 3) (bank-conflict-free reads).
    const int bcol4 = tid >> 2;
    const int bslot = tid & 3;

    float4 rcur[4], rnext[4];
    auto loadA = [&](int ks, float4* r) {
#pragma unroll
        for (int rg = 0; rg < 4; ++rg)
            r[rg] = *(const float4*)(ag + (size_t)rg * 32 * 512 + ks * 32);
    };
    auto writeA = [&](int p, const float4* r) {
#pragma unroll
        for (int rg = 0; rg < 4; ++rg) {
            bf16x4 c;
            c[0] = (bf16)r[rg].x; c[1] = (bf16)r[rg].y;
            c[2] = (bf16)r[rg].z; c[3] = (bf16)r[rg].w;
            *(bf16x4*)(&As[p][(rg * 32 + arow8) * 40 + acol8 * 4]) = c;
        }
    };
    auto issueB = [&](int ks, int p) {
#pragma unroll
        for (int r = 0; r < 4; ++r) {
            int c = r * 64 + bcol4;
            int g = bslot ^ ((c + (c >> 2)) & 3);
            async_copy16(WT + (size_t)c * 512 + ks * 32 + g * 8,
                         &Bs[p][r * 2048 + tid * 8]);
        }
    };

    // prologue: buffer0 <- step 0; rcur <- A(1)
    loadA(0, rcur);
    issueB(0, 0);
    writeA(0, rcur);
    loadA(1, rcur);
    __syncthreads();

    for (int ks = 0; ks < 16; ++ks) {
        const int p = ks & 1;
        if (ks < 14) loadA(ks + 2, rnext);       // HBM prefetch, 2 steps ahead
        if (ks < 15) {
            writeA(1 - p, rcur);                 // rcur = A(ks+1), already landed
            issueB(ks + 1, 1 - p);               // L2-resident async -> LDS
        }
        // fragments + MFMAs on buffer p
        bf16x8 af[4];
#pragma unroll
        for (int mt = 0; mt < 4; ++mt) {
            int row = mrow0 + mt * 16 + l15;
            af[mt] = *(const bf16x8*)(&As[p][row * 40 + q * 8]);
        }
        bf16x8 bfr[8];
#pragma unroll
        for (int nt = 0; nt < 8; ++nt) {
            int col = ncol0 + nt * 16 + l15;
            int pc = q ^ ((col + (col >> 2)) & 3);
            bfr[nt] = *(const bf16x8*)(&Bs[p][col * 32 + pc * 8]);
        }
#pragma unroll
        for (int mt = 0; mt < 4; ++mt)
#pragma unroll
            for (int nt = 0; nt < 8; ++nt)
                acc[mt][nt] = __builtin_amdgcn_mfma_f32_16x16x32_bf16(af[mt], bfr[nt], acc[mt][nt], 0, 0, 0);
        __syncthreads();
#pragma unroll
        for (int i = 0; i < 4; ++i) rcur[i] = rnext[i];
    }

    // ---- epilogue: scores[row] = sum_col tanh(C + dp[col]) * v[col] ----
    // C/D layout: col = l15 + 16*nt, row_local = q*4 + reg
#pragma unroll
    for (int mt = 0; mt < 4; ++mt) {
#pragma unroll
        for (int r = 0; r < 4; ++r) {
            float s = 0.f;
#pragma unroll
            for (int nt = 0; nt < 8; ++nt)
                s += fast_tanh(acc[mt][nt][r] + dpv[nt]) * vv[nt];
            s += __shfl_xor(s, 1, 16);
            s += __shfl_xor(s, 2, 16);
            s += __shfl_xor(s, 4, 16);
            s += __shfl_xor(s, 8, 16);
            if (l15 == 0)
                partial[wave][mt * 16 + q * 4 + r] = s;
        }
    }
    __syncthreads();
    if (tid < 128) {
        int mw   = tid >> 6;
        int rloc = tid & 63;
        out_scores[m0 + mw * 64 + rloc] =
            partial[mw * 2][rloc] + partial[mw * 2 + 1][rloc];
    }
}

// ---------------- context + fused softmax ---------------------------------
// grid = 64 b x 16 slabs (128 rows). Each block recomputes batch softmax
// stats from scores (L2-hot, deterministic per batch); slab 0 writes the
// attn weights to d_out. Streaming: 256 threads sweep 2 rows (4 KB) per
// iter, lane-contiguous.
__global__ __launch_bounds__(256) void k_context(const float* __restrict__ enc,
                                                 const float* __restrict__ scores,
                                                 float* __restrict__ attn_out,
                                                 float* __restrict__ partial) {
    const int b    = blockIdx.x >> 4;
    const int slab = blockIdx.x & 15;
    const int tid  = threadIdx.x;
    const float* sc = scores + b * 2048;

    __shared__ float red[256];
    __shared__ float wl[128];
    __shared__ f32x4 r2[128];

    // softmax stats over the full 2048 scores
    float x[8];
    float mx = -1e30f;
#pragma unroll
    for (int i = 0; i < 8; ++i) { x[i] = sc[tid + 256 * i]; mx = fmaxf(mx, x[i]); }
    red[tid] = mx;
    __syncthreads();
    for (int off = 128; off > 0; off >>= 1) {
        if (tid < off) red[tid] = fmaxf(red[tid], red[tid + off]);
        __syncthreads();
    }
    mx = red[0];
    __syncthreads();
    float e[8], ls = 0.f;
#pragma unroll
    for (int i = 0; i < 8; ++i) { e[i] = fexp2((x[i] - mx) * 1.4426950408889634f); ls += e[i]; }
    red[tid] = ls;
    __syncthreads();
    for (int off = 128; off > 0; off >>= 1) {
        if (tid < off) red[tid] += red[tid + off];
        __syncthreads();
    }
    const float inv = 1.0f / red[0];

    // slab-local weights into LDS; slab 0 also publishes attn weights
    if (tid < 128) {
        float s0 = sc[slab * 128 + tid];
        wl[tid] = fexp2((s0 - mx) * 1.4426950408889634f) * inv;
    }
    if (slab == 0) {
#pragma unroll
        for (int i = 0; i < 8; ++i)
            attn_out[b * 2048 + tid + 256 * i] = e[i] * inv;
    }
    __syncthreads();

    // weighted accumulation over this slab's 128 rows
    const float* eb = enc + ((size_t)b * 2048 + slab * 128) * 512;
    const int half = tid >> 7;            // 0/1 -> row parity
    const int col4 = tid & 127;           // float4 column index
    f32x4 acc = {0.f, 0.f, 0.f, 0.f};
#pragma unroll 8
    for (int s2 = 0; s2 < 64; ++s2) {
        int row = s2 * 2 + half;
        float ws = wl[row];
        f32x4 ev = *(const f32x4*)(eb + (size_t)row * 512 + col4 * 4);
        acc += ev * ws;
    }
    if (half) r2[col4] = acc;
    __syncthreads();
    if (!half) {
        acc += r2[col4];
        *(f32x4*)(partial + (size_t)blockIdx.x * 512 + col4 * 4) = acc;
    }
}

// ---------------- context reduce: 16 slabs -> ctx --------------------------
__global__ __launch_bounds__(128) void k_ctxred(const float* __restrict__ partial,
                                                float* __restrict__ ctx) {
    int b  = blockIdx.x;
    int eq = threadIdx.x;                 // e = eq*4
    f32x4 a = {0.f, 0.f, 0.f, 0.f};
#pragma unroll
    for (int slab = 0; slab < 16; ++slab)
        a += *(const f32x4*)(partial + ((size_t)b * 16 + slab) * 512 + eq * 4);
    *(f32x4*)(ctx + b * 512 + eq * 4) = a;
}

extern "C" void kernel_launch(void* const* d_in, const int* in_sizes, int n_in,
                              void* d_out, int out_size, void* d_ws, size_t ws_size,
                              hipStream_t stream) {
    const float* enc       = (const float*)d_in[0];
    const float* dec_state = (const float*)d_in[1];
    const float* W_enc     = (const float*)d_in[2];
    const float* W_dec     = (const float*)d_in[3];
    const float* v         = (const float*)d_in[4];

    float* ctx  = (float*)d_out;                 // [64,512]
    float* attn = (float*)d_out + 64 * 512;      // [64,2048] final weights

    // ws: WT bf16 256KB | dp 64KB | scores 512KB | partial 2MB
    char*  ws        = (char*)d_ws;
    bf16*  WT        = (bf16*)ws;
    float* dp        = (float*)(ws + 262144);
    float* scores_ws = (float*)(ws + 262144 + 65536);
    float* partial   = (float*)(ws + 262144 + 65536 + 524288);

    k_setup  <<<576, 256, 0, stream>>>(W_enc, dec_state, W_dec, WT, dp);
    k_scores <<<1024, 256, 0, stream>>>(enc, WT, dp, v, scores_ws);
    k_context<<<1024, 256, 0, stream>>>(enc, scores_ws, attn, partial);
    k_ctxred <<<64, 128, 0, stream>>>(partial, ctx);
}